// Round 4
// baseline (1284.516 us; speedup 1.0000x reference)
//
#include <hip/hip_runtime.h>
#include <hip/hip_bf16.h>
#include <math.h>

#define N_NODES 50000
#define N_EDGES 800000
#define NUM_GRAPHS 500
#define F_IN 128
#define HID 256
#define NCLS 10

// ---------------- GEMM: C[N,M] = A[N,K] @ B[K,M] (+ bias) ----------------
// 128x128 tile, BK=16, 256 threads, 8x8 accum, register-prefetch pipeline.
#define TBM 128
#define TBN 128
#define TBK 16

__global__ __launch_bounds__(256) void gemm_bias(
    const float* __restrict__ A, const float* __restrict__ B,
    const float* __restrict__ bias, float* __restrict__ C,
    int N, int K, int M) {
  __shared__ float As[TBK][TBM + 4];  // transposed A tile
  __shared__ float Bs[TBK][TBN];
  const int row0 = blockIdx.x * TBM;
  const int col0 = blockIdx.y * TBN;
  const int t = threadIdx.x;
  const int tx = t & 15, ty = t >> 4;
  const int rA0 = t >> 2, kA = (t & 3) * 4;  // A: rows 0..63 (+64), k-vec
  const int kB0 = t >> 5, cB = (t & 31) * 4; // B: k 0..7 (+8), col-vec
  float acc[8][8] = {};
  float4 a0, a1, b0, b1;

  auto gload = [&](int k0) {
    int gr0 = row0 + rA0, gr1 = row0 + rA0 + 64;
    a0 = (gr0 < N) ? *(const float4*)(A + (size_t)gr0 * K + k0 + kA)
                   : make_float4(0.f, 0.f, 0.f, 0.f);
    a1 = (gr1 < N) ? *(const float4*)(A + (size_t)gr1 * K + k0 + kA)
                   : make_float4(0.f, 0.f, 0.f, 0.f);
    b0 = *(const float4*)(B + (size_t)(k0 + kB0) * M + col0 + cB);
    b1 = *(const float4*)(B + (size_t)(k0 + kB0 + 8) * M + col0 + cB);
  };
  auto lstore = [&]() {
    As[kA + 0][rA0] = a0.x; As[kA + 1][rA0] = a0.y;
    As[kA + 2][rA0] = a0.z; As[kA + 3][rA0] = a0.w;
    As[kA + 0][rA0 + 64] = a1.x; As[kA + 1][rA0 + 64] = a1.y;
    As[kA + 2][rA0 + 64] = a1.z; As[kA + 3][rA0 + 64] = a1.w;
    *(float4*)&Bs[kB0][cB] = b0;
    *(float4*)&Bs[kB0 + 8][cB] = b1;
  };
  auto fma_tile = [&]() {
#pragma unroll
    for (int k = 0; k < TBK; ++k) {
      float a[8], b[8];
      *(float4*)&a[0] = *(const float4*)&As[k][ty * 4];
      *(float4*)&a[4] = *(const float4*)&As[k][ty * 4 + 64];
      *(float4*)&b[0] = *(const float4*)&Bs[k][tx * 4];
      *(float4*)&b[4] = *(const float4*)&Bs[k][tx * 4 + 64];
#pragma unroll
      for (int i = 0; i < 8; ++i)
#pragma unroll
        for (int j = 0; j < 8; ++j) acc[i][j] += a[i] * b[j];
    }
  };

  gload(0);
  lstore();
  __syncthreads();
  for (int k0 = TBK; k0 < K; k0 += TBK) {
    gload(k0);      // prefetch next tile into registers (latency hides under FMA)
    fma_tile();     // compute on current LDS tile
    __syncthreads();
    lstore();
    __syncthreads();
  }
  fma_tile();

#pragma unroll
  for (int ih = 0; ih < 2; ++ih) {
#pragma unroll
    for (int i = 0; i < 4; ++i) {
      int gr = row0 + ih * 64 + ty * 4 + i;
      if (gr < N) {
#pragma unroll
        for (int jh = 0; jh < 2; ++jh) {
          int gc = col0 + jh * 64 + tx * 4;
          float4 v;
          v.x = acc[ih * 4 + i][jh * 4 + 0];
          v.y = acc[ih * 4 + i][jh * 4 + 1];
          v.z = acc[ih * 4 + i][jh * 4 + 2];
          v.w = acc[ih * 4 + i][jh * 4 + 3];
          if (bias) {
            v.x += bias[gc + 0];
            v.y += bias[gc + 1];
            v.z += bias[gc + 2];
            v.w += bias[gc + 3];
          }
          *(float4*)(C + (size_t)gr * M + gc) = v;
        }
      }
    }
  }
}

// ---------------- degree accumulation (deg pre-zeroed; self-loop folded later) --
__global__ __launch_bounds__(256) void deg_accum(
    const int* __restrict__ dst, const float* __restrict__ ew,
    float* deg, int* cnt, int E) {
  int e = blockIdx.x * 256 + threadIdx.x;
  if (e < E) {
    int d = dst[e];
    atomicAdd(&deg[d], ew[e]);
    atomicAdd(&cnt[d], 1);
  }
}

// ---------------- hierarchical exclusive scan + dinv ----------------
// phase 1: per-256-block sums of cnt; also dinv[i] = rsqrt(deg[i] + 1)
__global__ __launch_bounds__(256) void scan_p1(const int* __restrict__ cnt,
                                               const float* __restrict__ deg,
                                               float* __restrict__ dinv,
                                               int* __restrict__ bsum, int n) {
  __shared__ int s[256];
  int i = blockIdx.x * 256 + threadIdx.x;
  s[threadIdx.x] = (i < n) ? cnt[i] : 0;
  if (i < n) dinv[i] = rsqrtf(deg[i] + 1.0f);  // deg+self>=1, always >0
  __syncthreads();
  for (int off = 128; off > 0; off >>= 1) {
    if (threadIdx.x < off) s[threadIdx.x] += s[threadIdx.x + off];
    __syncthreads();
  }
  if (threadIdx.x == 0) bsum[blockIdx.x] = s[0];
}

__global__ __launch_bounds__(256) void scan_p2(int* __restrict__ bsum, int nb,
                                               int* __restrict__ total_out) {
  __shared__ int s[256];
  int t = threadIdx.x;
  int v = (t < nb) ? bsum[t] : 0;
  s[t] = v;
  __syncthreads();
  for (int off = 1; off < 256; off <<= 1) {
    int u = (t >= off) ? s[t - off] : 0;
    __syncthreads();
    s[t] += u;
    __syncthreads();
  }
  if (t < nb) bsum[t] = s[t] - v;  // exclusive
  if (t == 255) *total_out = s[255];
}

__global__ __launch_bounds__(256) void scan_p3(const int* __restrict__ cnt,
                                               const int* __restrict__ bsum,
                                               int* __restrict__ row_ptr, int n) {
  __shared__ int s[256];
  int i = blockIdx.x * 256 + threadIdx.x;
  int t = threadIdx.x;
  int v = (i < n) ? cnt[i] : 0;
  s[t] = v;
  __syncthreads();
  for (int off = 1; off < 256; off <<= 1) {
    int u = (t >= off) ? s[t - off] : 0;
    __syncthreads();
    s[t] += u;
    __syncthreads();
  }
  if (i < n) row_ptr[i] = bsum[blockIdx.x] + s[t] - v;
}

// ---------------- CSR fill: (src, coef) packed as int2 ----------------
__global__ __launch_bounds__(256) void csr_fill(
    const int* __restrict__ src, const int* __restrict__ dst,
    const float* __restrict__ ew, const float* __restrict__ dinv,
    const int* __restrict__ row_ptr, int* cursor,
    int2* __restrict__ csr_ent, int E) {
  int e = blockIdx.x * 256 + threadIdx.x;
  if (e < E) {
    int s = src[e], d = dst[e];
    int pos = atomicAdd(&cursor[d], 1);
    int idx = row_ptr[d] + pos;
    float coef = dinv[s] * ew[e] * dinv[d];
    csr_ent[idx] = make_int2(s, __float_as_int(coef));
  }
}

// ------- aggregation + bias + ELU: one wave per node, 2 nodes per block -------
__global__ __launch_bounds__(128) void gather_elu(
    const float* __restrict__ hW, const float* __restrict__ dinv,
    const int* __restrict__ row_ptr, const int2* __restrict__ csr_ent,
    const float* __restrict__ bias, float* __restrict__ out) {
  const int wave = threadIdx.x >> 6;
  const int lane = threadIdx.x & 63;
  const int n = blockIdx.x * 2 + wave;
  if (n >= N_NODES) return;
  const float4* hw4 = (const float4*)hW;  // 64 float4 per row
  const int start = row_ptr[n], end = row_ptr[n + 1];
  const float di = dinv[n];
  const float cself = di * di;
  float4 h = hw4[(size_t)n * 64 + lane];
  float4 acc;
  acc.x = cself * h.x; acc.y = cself * h.y;
  acc.z = cself * h.z; acc.w = cself * h.w;
  int e = start;
  for (; e + 2 <= end; e += 2) {
    int4 ee = *(const int4*)&csr_ent[e];  // two packed entries in one load
    float4 v0 = hw4[(size_t)ee.x * 64 + lane];
    float4 v1 = hw4[(size_t)ee.z * 64 + lane];
    float w0 = __int_as_float(ee.y), w1 = __int_as_float(ee.w);
    acc.x += w0 * v0.x + w1 * v1.x;
    acc.y += w0 * v0.y + w1 * v1.y;
    acc.z += w0 * v0.z + w1 * v1.z;
    acc.w += w0 * v0.w + w1 * v1.w;
  }
  if (e < end) {
    int2 e0 = csr_ent[e];
    float w0 = __int_as_float(e0.y);
    float4 v0 = hw4[(size_t)e0.x * 64 + lane];
    acc.x += w0 * v0.x;
    acc.y += w0 * v0.y;
    acc.z += w0 * v0.z;
    acc.w += w0 * v0.w;
  }
  float4 bb = ((const float4*)bias)[lane];
  acc.x += bb.x; acc.y += bb.y; acc.z += bb.z; acc.w += bb.w;
  acc.x = (acc.x > 0.f) ? acc.x : expm1f(acc.x);
  acc.y = (acc.y > 0.f) ? acc.y : expm1f(acc.y);
  acc.z = (acc.z > 0.f) ? acc.z : expm1f(acc.z);
  acc.w = (acc.w > 0.f) ? acc.w : expm1f(acc.w);
  ((float4*)out)[(size_t)n * 64 + lane] = acc;
}

// ---------------- pooling (sorted batch -> ranges) + final linear ----------------
__global__ __launch_bounds__(256) void find_start(const int* __restrict__ batch,
                                                  int* __restrict__ gstart) {
  int g = blockIdx.x * 256 + threadIdx.x;
  if (g <= NUM_GRAPHS) {
    int lo = 0, hi = N_NODES;
    while (lo < hi) {
      int mid = (lo + hi) >> 1;
      if (batch[mid] < g) lo = mid + 1; else hi = mid;
    }
    gstart[g] = lo;
  }
}

__global__ __launch_bounds__(256) void pool_final(
    const float* __restrict__ h, const int* __restrict__ gstart,
    const float* __restrict__ W, const float* __restrict__ b,
    float* __restrict__ out) {
  int g = blockIdx.x;
  __shared__ float part[NCLS * 256];
  int f = threadIdx.x;
  int s = gstart[g], e = gstart[g + 1];
  float sum = 0.f;
  for (int n = s; n < e; ++n) sum += h[(size_t)n * HID + f];
  float v = sum / fmaxf((float)(e - s), 1.0f);
#pragma unroll
  for (int c = 0; c < NCLS; ++c) part[c * 256 + f] = v * W[f * NCLS + c];
  __syncthreads();
  for (int off = 128; off > 0; off >>= 1) {
    if (f < off) {
#pragma unroll
      for (int c = 0; c < NCLS; ++c) part[c * 256 + f] += part[c * 256 + f + off];
    }
    __syncthreads();
  }
  if (f < NCLS) out[g * NCLS + f] = part[f * 256] + b[f];
}

extern "C" void kernel_launch(void* const* d_in, const int* in_sizes, int n_in,
                              void* d_out, int out_size, void* d_ws, size_t ws_size,
                              hipStream_t stream) {
  const float* x = (const float*)d_in[0];
  const int* ei = (const int*)d_in[1];
  const int* e_src = ei;
  const int* e_dst = ei + N_EDGES;
  const float* ea = (const float*)d_in[2];
  // d_in[3] = edge_type: unused (edge_dim=1 mixing carries no per-type params)
  const int* batch = (const int*)d_in[4];
  const float* enc1_w = (const float*)d_in[5];
  const float* enc1_b = (const float*)d_in[6];
  const float* enc2_w = (const float*)d_in[7];
  const float* enc2_b = (const float*)d_in[8];
  const float* conv_ws = (const float*)d_in[9];
  const float* conv_bs = (const float*)d_in[10];
  const float* lin1_w = (const float*)d_in[11];
  const float* lin1_b = (const float*)d_in[12];
  float* out = (float*)d_out;

  char* w = (char*)d_ws;
  size_t off = 0;
  auto alloc = [&](size_t bytes) {
    size_t o = off;
    off = (off + bytes + 255) & ~(size_t)255;
    return (void*)(w + o);
  };
  float* bufA = (float*)alloc((size_t)N_NODES * HID * 4);
  float* bufB = (float*)alloc((size_t)N_NODES * HID * 4);
  float* deg = (float*)alloc((size_t)N_NODES * 4);
  float* dinv = (float*)alloc((size_t)N_NODES * 4);
  int* cnt = (int*)alloc((size_t)N_NODES * 4);
  int* row_ptr = (int*)alloc((size_t)(N_NODES + 1) * 4);
  int* cursor = (int*)alloc((size_t)N_NODES * 4);
  int* bsum = (int*)alloc((size_t)256 * 4);
  int2* csr_ent = (int2*)alloc((size_t)N_EDGES * 8);
  int* gstart = (int*)alloc((size_t)(NUM_GRAPHS + 1) * 4);
  (void)ws_size; (void)in_sizes; (void)n_in; (void)out_size;

  hipMemsetAsync(deg, 0, (size_t)N_NODES * 4, stream);
  hipMemsetAsync(cnt, 0, (size_t)N_NODES * 4, stream);
  hipMemsetAsync(cursor, 0, (size_t)N_NODES * 4, stream);

  const int nb_nodes = (N_NODES + 255) / 256;  // 196
  const int nb_edges = (N_EDGES + 255) / 256;

  // graph normalization + CSR (independent of features; built once per call)
  deg_accum<<<nb_edges, 256, 0, stream>>>(e_dst, ea, deg, cnt, N_EDGES);
  scan_p1<<<nb_nodes, 256, 0, stream>>>(cnt, deg, dinv, bsum, N_NODES);
  scan_p2<<<1, 256, 0, stream>>>(bsum, nb_nodes, row_ptr + N_NODES);
  scan_p3<<<nb_nodes, 256, 0, stream>>>(cnt, bsum, row_ptr, N_NODES);
  csr_fill<<<nb_edges, 256, 0, stream>>>(e_src, e_dst, ea, dinv, row_ptr, cursor,
                                         csr_ent, N_EDGES);
  find_start<<<(NUM_GRAPHS + 256) / 256, 256, 0, stream>>>(batch, gstart);

  const int gR = (N_NODES + TBM - 1) / TBM;  // 391

  // encoder: h0 = x@enc1_w + b (N,128) -> bufB ; h1 = h0@enc2_w + b (N,256) -> bufA
  {
    dim3 grid(gR, F_IN / TBN);
    gemm_bias<<<grid, 256, 0, stream>>>(x, enc1_w, enc1_b, bufB, N_NODES, F_IN, F_IN);
  }
  {
    dim3 grid(gR, HID / TBN);
    gemm_bias<<<grid, 256, 0, stream>>>(bufB, enc2_w, enc2_b, bufA, N_NODES, F_IN, HID);
  }

  // 4 GCN layers: hW = h@W (bufA->bufB); aggregate+bias+ELU (bufB->bufA)
  for (int layer = 0; layer < 4; ++layer) {
    dim3 grid(gR, HID / TBN);
    gemm_bias<<<grid, 256, 0, stream>>>(bufA, conv_ws + (size_t)layer * HID * HID,
                                        nullptr, bufB, N_NODES, HID, HID);
    gather_elu<<<(N_NODES + 1) / 2, 128, 0, stream>>>(
        bufB, dinv, row_ptr, csr_ent,
        conv_bs + (size_t)layer * HID, bufA);
  }

  // deterministic mean-pool per graph + final linear (fused)
  pool_final<<<NUM_GRAPHS, 256, 0, stream>>>(bufA, gstart, lin1_w, lin1_b, out);
}